// Round 1
// baseline (450.273 us; speedup 1.0000x reference)
//
#include <hip/hip_runtime.h>
#include <hip/hip_bf16.h>

#define NB 32
#define NS 2048
#define NDD 1024
#define NDE 1024
#define NDA 1024
#define NEGV (-1000000000.0f)

typedef __attribute__((ext_vector_type(8))) __bf16 bf16x8;
typedef __attribute__((ext_vector_type(4))) float f32x4;

__device__ __forceinline__ float fast_tanh(float x) {
    x = fminf(10.0f, fmaxf(-10.0f, x));
    float e = __expf(2.0f * x);
    return __fdividef(e - 1.0f, e + 1.0f);
}

// ---------------- We (f32) -> bf16 conversion ----------------
__global__ void prep_we(const float* __restrict__ Wc, __bf16* __restrict__ We) {
    int f = blockIdx.x * 256 + threadIdx.x;       // float4 index, total 1024*1024/4
    int a  = f >> 8;                              // 256 float4 per row
    int k4 = f & 255;
    float4 v = *reinterpret_cast<const float4*>(Wc + (size_t)a * (NDD + NDE) + NDD + k4 * 4);
    union { __bf16 h[4]; uint2 u; } pk;
    pk.h[0] = (__bf16)v.x; pk.h[1] = (__bf16)v.y;
    pk.h[2] = (__bf16)v.z; pk.h[3] = (__bf16)v.w;
    *reinterpret_cast<uint2*>(We + (size_t)a * NDE + k4 * 4) = pk.u;
}

// ---------------- q_proj = query @ Wq^T (f32, exact) ----------------
__global__ void qproj_kernel(const float* __restrict__ q, const float* __restrict__ Wc,
                             float* __restrict__ qp) {
    __shared__ float qs[NDD];
    int b = blockIdx.y;
    int a = blockIdx.x * 256 + threadIdx.x;
    float4 qv = *reinterpret_cast<const float4*>(q + (size_t)b * NDD + threadIdx.x * 4);
    *reinterpret_cast<float4*>(qs + threadIdx.x * 4) = qv;
    __syncthreads();
    const float* wrow = Wc + (size_t)a * (NDD + NDE);
    float acc = 0.f;
#pragma unroll 4
    for (int k4 = 0; k4 < 256; ++k4) {
        float4 w = *reinterpret_cast<const float4*>(wrow + k4 * 4);
        acc += qs[k4*4+0] * w.x + qs[k4*4+1] * w.y + qs[k4*4+2] * w.z + qs[k4*4+3] * w.w;
    }
    qp[(size_t)b * NDA + a] = acc;
}

// ---------------- fused e_proj GEMM + tanh + V-dot + mask -> scores ----------------
// block: 64 rows x (a = all 1024) x (K = 1024).  8 waves, wave w owns a-range [w*128, w*128+128)
// LDS: double-buffered 64x128 bf16 E-chunks (XOR-swizzled), accs persist across K.
__global__ __launch_bounds__(512) void score_kernel(
    const float* __restrict__ E, const __bf16* __restrict__ We,
    const float* __restrict__ qp, const float* __restrict__ Vv,
    const int* __restrict__ mask, float* __restrict__ scores) {
    __shared__ __align__(16) unsigned char ebuf[2][64 * 128 * 2];  // 2 x 16 KB
    __shared__ float score_lds[64];

    const int tid  = threadIdx.x;
    const int lane = tid & 63;
    const int wave = tid >> 6;
    const int row0 = blockIdx.x * 64;
    const int b    = row0 >> 11;           // row0 / 2048
    const int a0   = wave * 128;

    if (tid < 64) score_lds[tid] = 0.f;

    f32x4 acc[4][8];
#pragma unroll
    for (int mf = 0; mf < 4; ++mf)
#pragma unroll
        for (int nf = 0; nf < 8; ++nf)
            acc[mf][nf] = (f32x4){0.f, 0.f, 0.f, 0.f};

    // b-frag base: lane reads We row n = a0 + nf*16 + (lane&15), k offset (lane>>4)*8
    const __bf16* wbase = We + (size_t)(a0 + (lane & 15)) * NDE + ((lane >> 4) * 8);

    // ---- prologue: stage chunk 0 ----
    float4 st[4];
#pragma unroll
    for (int j = 0; j < 4; ++j) {
        int f = tid + 512 * j;             // float4 idx within chunk (2048 total)
        int r = f >> 5, k4 = f & 31;       // 32 float4 per row
        st[j] = *reinterpret_cast<const float4*>(E + (size_t)(row0 + r) * NDE + k4 * 4);
    }
#pragma unroll
    for (int j = 0; j < 4; ++j) {
        int f = tid + 512 * j;
        int r = f >> 5, k4 = f & 31;
        int off = (r * 256 + k4 * 8) ^ ((r & 7) << 4);
        union { __bf16 h[4]; uint2 u; } pk;
        pk.h[0] = (__bf16)st[j].x; pk.h[1] = (__bf16)st[j].y;
        pk.h[2] = (__bf16)st[j].z; pk.h[3] = (__bf16)st[j].w;
        *reinterpret_cast<uint2*>(&ebuf[0][off]) = pk.u;
    }
    __syncthreads();

    for (int c = 0; c < 8; ++c) {
        if (c < 7) {  // issue next chunk's global loads early (hide under MFMAs)
#pragma unroll
            for (int j = 0; j < 4; ++j) {
                int f = tid + 512 * j;
                int r = f >> 5, k4 = f & 31;
                st[j] = *reinterpret_cast<const float4*>(
                    E + (size_t)(row0 + r) * NDE + (c + 1) * 128 + k4 * 4);
            }
        }
        const unsigned char* buf = ebuf[c & 1];
#pragma unroll
        for (int ks = 0; ks < 4; ++ks) {
            bf16x8 af[4];
#pragma unroll
            for (int mf = 0; mf < 4; ++mf) {
                int r = mf * 16 + (lane & 15);
                int off = (r * 256 + ks * 64 + (lane >> 4) * 16) ^ ((r & 7) << 4);
                af[mf] = *reinterpret_cast<const bf16x8*>(buf + off);
            }
            bf16x8 bfr[8];
#pragma unroll
            for (int nf = 0; nf < 8; ++nf)
                bfr[nf] = *reinterpret_cast<const bf16x8*>(wbase + (size_t)nf * 16 * NDE + c * 128 + ks * 32);
#pragma unroll
            for (int mf = 0; mf < 4; ++mf)
#pragma unroll
                for (int nf = 0; nf < 8; ++nf)
                    acc[mf][nf] = __builtin_amdgcn_mfma_f32_16x16x32_bf16(
                        af[mf], bfr[nf], acc[mf][nf], 0, 0, 0);
        }
        __syncthreads();
        if (c < 7) {
#pragma unroll
            for (int j = 0; j < 4; ++j) {
                int f = tid + 512 * j;
                int r = f >> 5, k4 = f & 31;
                int off = (r * 256 + k4 * 8) ^ ((r & 7) << 4);
                union { __bf16 h[4]; uint2 u; } pk;
                pk.h[0] = (__bf16)st[j].x; pk.h[1] = (__bf16)st[j].y;
                pk.h[2] = (__bf16)st[j].z; pk.h[3] = (__bf16)st[j].w;
                *reinterpret_cast<uint2*>(&ebuf[(c + 1) & 1][off]) = pk.u;
            }
            __syncthreads();
        }
    }

    // ---- epilogue: tanh(qp + e_proj) * V, reduce over a ----
    float ps[4][4];
#pragma unroll
    for (int mf = 0; mf < 4; ++mf)
#pragma unroll
        for (int j = 0; j < 4; ++j) ps[mf][j] = 0.f;

#pragma unroll
    for (int nf = 0; nf < 8; ++nf) {
        int n = a0 + nf * 16 + (lane & 15);
        float qv = qp[(size_t)b * NDA + n];
        float vv = Vv[n];
#pragma unroll
        for (int mf = 0; mf < 4; ++mf)
#pragma unroll
            for (int j = 0; j < 4; ++j)
                ps[mf][j] += fast_tanh(qv + acc[mf][nf][j]) * vv;
    }
    // reduce across the 16 lanes sharing the same output row
#pragma unroll
    for (int mf = 0; mf < 4; ++mf)
#pragma unroll
        for (int j = 0; j < 4; ++j) {
            float v = ps[mf][j];
            v += __shfl_xor(v, 1);
            v += __shfl_xor(v, 2);
            v += __shfl_xor(v, 4);
            v += __shfl_xor(v, 8);
            if ((lane & 15) == 0)
                atomicAdd(&score_lds[mf * 16 + (lane >> 4) * 4 + j], v);
        }
    __syncthreads();
    if (tid < 64) {
        int rowg = row0 + tid;
        int s = rowg & (NS - 1);
        float sc = score_lds[tid];
        scores[rowg] = (mask[(size_t)b * NS + s] == 0) ? NEGV : sc;
    }
}

// ---------------- softmax over s, per b ----------------
__global__ void softmax_kernel(const float* __restrict__ scores, float* __restrict__ wout) {
    int b = blockIdx.x;
    const float* srow = scores + (size_t)b * NS;
    float v[8];
    float lmax = -INFINITY;
#pragma unroll
    for (int j = 0; j < 8; ++j) {
        v[j] = srow[threadIdx.x + 256 * j];
        lmax = fmaxf(lmax, v[j]);
    }
#pragma unroll
    for (int m = 1; m <= 32; m <<= 1) lmax = fmaxf(lmax, __shfl_xor(lmax, m));
    __shared__ float redm[4], reds[4];
    if ((threadIdx.x & 63) == 0) redm[threadIdx.x >> 6] = lmax;
    __syncthreads();
    float bmax = fmaxf(fmaxf(redm[0], redm[1]), fmaxf(redm[2], redm[3]));
    float lsum = 0.f;
#pragma unroll
    for (int j = 0; j < 8; ++j) { v[j] = __expf(v[j] - bmax); lsum += v[j]; }
#pragma unroll
    for (int m = 1; m <= 32; m <<= 1) lsum += __shfl_xor(lsum, m);
    if ((threadIdx.x & 63) == 0) reds[threadIdx.x >> 6] = lsum;
    __syncthreads();
    float inv = __fdividef(1.0f, reds[0] + reds[1] + reds[2] + reds[3]);
#pragma unroll
    for (int j = 0; j < 8; ++j) wout[(size_t)b * NS + threadIdx.x + 256 * j] = v[j] * inv;
}

// ---------------- context = w @ E ----------------
// grid 256: b = bx>>3, d-chunk (128 d) = bx&7.  256 thr: 64 float2-lanes x 4-way s-split.
__global__ void context_kernel(const float* __restrict__ E, const float* __restrict__ w,
                               float* __restrict__ ctx) {
    int b  = blockIdx.x >> 3;
    int dc = blockIdx.x & 7;
    int d2 = dc * 64 + (threadIdx.x & 63);      // float2 index within row (512 per row)
    int s0 = (threadIdx.x >> 6) * 512;
    const float2* Eb = reinterpret_cast<const float2*>(E) + (size_t)b * NS * (NDE / 2);
    const float* wb = w + (size_t)b * NS;
    float ax = 0.f, ay = 0.f;
#pragma unroll 8
    for (int s = s0; s < s0 + 512; ++s) {
        float ws = wb[s];
        float2 e = Eb[(size_t)s * (NDE / 2) + d2];
        ax = fmaf(ws, e.x, ax);
        ay = fmaf(ws, e.y, ay);
    }
    __shared__ float2 part[256];
    part[threadIdx.x] = make_float2(ax, ay);
    __syncthreads();
    if (threadIdx.x < 64) {
        float2 p0 = part[threadIdx.x], p1 = part[threadIdx.x + 64];
        float2 p2 = part[threadIdx.x + 128], p3 = part[threadIdx.x + 192];
        float2 r = make_float2(p0.x + p1.x + p2.x + p3.x, p0.y + p1.y + p2.y + p3.y);
        reinterpret_cast<float2*>(ctx + (size_t)b * NDD + dc * 128)[threadIdx.x] = r;
    }
}

extern "C" void kernel_launch(void* const* d_in, const int* in_sizes, int n_in,
                              void* d_out, int out_size, void* d_ws, size_t ws_size,
                              hipStream_t stream) {
    const float* query = (const float*)d_in[0];
    const float* enc   = (const float*)d_in[1];
    const int*   mask  = (const int*)d_in[2];
    const float* Wc    = (const float*)d_in[3];
    const float* V     = (const float*)d_in[4];

    float* out = (float*)d_out;
    float* ctx = out;                       // (32,1024)
    float* wts = out + NB * NDD;            // (32,2048)

    char* ws = (char*)d_ws;
    __bf16* We    = (__bf16*)ws;                                         // 2 MB
    float*  qp    = (float*)(ws + (size_t)NDA * NDE * 2);                // 128 KB
    float*  scores= (float*)(ws + (size_t)NDA * NDE * 2 + NB * NDA * 4); // 256 KB

    hipLaunchKernelGGL(prep_we,        dim3(1024),      dim3(256), 0, stream, Wc, We);
    hipLaunchKernelGGL(qproj_kernel,   dim3(4, NB),     dim3(256), 0, stream, query, Wc, qp);
    hipLaunchKernelGGL(score_kernel,   dim3(1024),      dim3(512), 0, stream, enc, We, qp, V, mask, scores);
    hipLaunchKernelGGL(softmax_kernel, dim3(NB),        dim3(256), 0, stream, scores, wts);
    hipLaunchKernelGGL(context_kernel, dim3(256),       dim3(256), 0, stream, enc, wts, ctx);
}